// Round 23
// baseline (175.465 us; speedup 1.0000x reference)
//
#include <hip/hip_runtime.h>
#include <hip/hip_bf16.h>

#define B_  16
#define S_  2048
#define F_  800
#define E_  200
#define EP  224          // padded E (multiple of 32)
#define KP  832          // padded K (26 * 32) — wt pitch only; K-loop runs 25 steps
#define KSP 256          // kbuf row pitch in shorts (32 x 16B slots, pow2 for swizzle)
#define M_  (B_ * S_)    // 32768

typedef __attribute__((ext_vector_type(8))) short short8;
typedef __attribute__((ext_vector_type(4))) float f32x4;

// scale = 1/sqrt(960); folded with log2(e) into Q so softmax runs in exp2 domain
#define QSCL (0.03227486121839514f * 1.4426950408889634f)

__device__ __forceinline__ unsigned short f2bf(float f) {
    __hip_bfloat16 h = __float2bfloat16(f);
    return *reinterpret_cast<unsigned short*>(&h);
}

__device__ __forceinline__ float exp2_fast(float x) {
    float r;
    asm("v_exp_f32 %0, %1" : "=v"(r) : "v"(x));
    return r;
}

__device__ __forceinline__ float rcp_fast(float x) {
    float r;
    asm("v_rcp_f32 %0, %1" : "=v"(r) : "v"(x));
    return r;
}

// tanh-form GELU (max |err| vs exact ~5e-4, below bf16 noise here)
__device__ __forceinline__ float gelu_fast(float x) {
    const float i = x + 0.044715f * x * x * x;
    const float z = 2.302265314f * i;              // 2*0.79788456*log2(e) * i
    return x * rcp_fast(1.0f + exp2_fast(-z));
}

__device__ __forceinline__ void gload_lds16(const void* g, void* l) {
    __builtin_amdgcn_global_load_lds(
        (const __attribute__((address_space(1))) unsigned int*)g,
        (__attribute__((address_space(3))) unsigned int*)l, 16, 0, 0);
}

// ---------------- prep: W^T bf16 padded wt[3][EP][KP] ----------------
__global__ __launch_bounds__(256)
void prep_w(const float* __restrict__ Wq, const float* __restrict__ Wk,
            const float* __restrict__ Wv, unsigned short* __restrict__ wt) {
    const int id = blockIdx.x * 256 + threadIdx.x;
    const int sel = id / (EP * KP);
    const int rem = id % (EP * KP);
    const int e = rem / KP;
    const int k = rem % KP;
    const float* W = (sel == 0) ? Wq : ((sel == 1) ? Wk : Wv);
    float v = (e < E_ && k < F_) ? W[(size_t)k * E_ + e] : 0.0f;
    wt[id] = f2bf(v);
}

// ---------------- Stage 1 GEMM: Q/K/V = gelu(X @ W), X read fp32 directly ----
// BM=128, BN=224, BK=32; 4 waves (2M x 2N); 25 K-steps (F=800 exactly, no pad
// step). X staged via registers (2x float4 -> 8x f2bf -> ds_write_b128, same
// swizzled layout as before: granule = pS ^ (row&3)); W staged via gload_lds
// (unchanged). prep_x kernel eliminated (-25us, -108MB HBM).
#define STAGE_X(XB, KK) do {                                                     \
    const int k0s = (KK) * 32;                                                   \
    _Pragma("unroll")                                                            \
    for (int i = 0; i < 2; ++i) {                                                \
        const int j = w * 2 + i;                                                 \
        const int row = 16 * j + rS;                                             \
        const float* xp = x + (size_t)(m0 + row) * F_ + k0s + pS * 8;            \
        const float4 a = *reinterpret_cast<const float4*>(xp);                   \
        const float4 bq = *reinterpret_cast<const float4*>(xp + 4);              \
        union { unsigned short u[8]; short8 s; } pk;                             \
        pk.u[0] = f2bf(a.x);  pk.u[1] = f2bf(a.y);                               \
        pk.u[2] = f2bf(a.z);  pk.u[3] = f2bf(a.w);                               \
        pk.u[4] = f2bf(bq.x); pk.u[5] = f2bf(bq.y);                              \
        pk.u[6] = f2bf(bq.z); pk.u[7] = f2bf(bq.w);                              \
        *reinterpret_cast<short8*>(                                              \
            &XB[row * 32 + ((pS ^ (rS & 3)) * 8)]) = pk.s;                       \
    }                                                                            \
} while (0)

#define STAGE_W(WB, KK) do {                                                     \
    const int k0s = (KK) * 32;                                                   \
    _Pragma("unroll")                                                            \
    for (int i = 0; i < 4; ++i) {                                                \
        const int j = i * 4 + w;                                                 \
        if (j < 14) {                                                            \
            const int row = 16 * j + rS;                                         \
            gload_lds16(wsel + (size_t)row * KP + k0s + ((pS ^ (row & 3)) * 8),  \
                        &WB[j * 512]);                                           \
        }                                                                        \
    }                                                                            \
} while (0)

#define STAGE(XB, WB, KK) do { STAGE_W(WB, KK); STAGE_X(XB, KK); } while (0)

#define COMPUTE(XB, WB) do {                                                     \
    short8 afr[4];                                                               \
    _Pragma("unroll")                                                            \
    for (int rf = 0; rf < 4; ++rf) {                                             \
        const int row = wr * 64 + rf * 16 + ln15;                                \
        afr[rf] = *reinterpret_cast<const short8*>(                              \
            &XB[row * 32 + ((g ^ (row & 3)) * 8)]);                              \
    }                                                                            \
    _Pragma("unroll")                                                            \
    for (int cf = 0; cf < 7; ++cf) {                                             \
        const int row = wc * 112 + cf * 16 + ln15;                               \
        short8 bfr = *reinterpret_cast<const short8*>(                           \
            &WB[row * 32 + ((g ^ (row & 3)) * 8)]);                              \
        _Pragma("unroll")                                                        \
        for (int rf = 0; rf < 4; ++rf)                                           \
            acc[rf][cf] = __builtin_amdgcn_mfma_f32_16x16x32_bf16(               \
                afr[rf], bfr, acc[rf][cf], 0, 0, 0);                             \
    }                                                                            \
} while (0)

__global__ __launch_bounds__(256, 2)
void gemm_qkv(const float* __restrict__ x,
              const unsigned short* __restrict__ wt,
              unsigned short* __restrict__ qbuf,
              unsigned short* __restrict__ kbuf,
              unsigned short* __restrict__ vtbuf) {
    const int sel = blockIdx.y;
    const int m0 = blockIdx.x * 128;
    const int t = threadIdx.x;
    const int lane = t & 63;
    const int w = t >> 6;
    const int wr = w >> 1;
    const int wc = w & 1;
    const int ln15 = lane & 15;
    const int g = lane >> 4;

    __shared__ __align__(16) unsigned short X0s[128 * 32];
    __shared__ __align__(16) unsigned short W0s[224 * 32];
    __shared__ __align__(16) unsigned short X1s[128 * 32];
    __shared__ __align__(16) unsigned short W1s[224 * 32];

    const unsigned short* wsel = wt + (size_t)sel * EP * KP;

    f32x4 acc[4][7];
#pragma unroll
    for (int i = 0; i < 4; ++i)
#pragma unroll
        for (int j = 0; j < 7; ++j) acc[i][j] = (f32x4)0.0f;

    const int rS = lane >> 2;            // staging row within 16-row chunk
    const int pS = lane & 3;             // staging logical granule (8 cols)

    STAGE(X0s, W0s, 0);
    __syncthreads();
#pragma unroll
    for (int p = 0; p < 12; ++p) {
        STAGE(X1s, W1s, 2 * p + 1);
        COMPUTE(X0s, W0s);
        __syncthreads();
        STAGE(X0s, W0s, 2 * p + 2);
        COMPUTE(X1s, W1s);
        __syncthreads();
    }
    COMPUTE(X0s, W0s);                   // kk = 24 (last real step; no pad step)

    // epilogue: gelu + store; V padding col 200 <- 1.0 (ones-column: PV
    // MFMA computes softmax denominators for free in attn)
#pragma unroll
    for (int rf = 0; rf < 4; ++rf) {
        const int row = m0 + wr * 64 + rf * 16 + g * 4;
#pragma unroll
        for (int cf = 0; cf < 7; ++cf) {
            const int col = wc * 112 + cf * 16 + ln15;
            if (sel == 0) {
#pragma unroll
                for (int tt = 0; tt < 4; ++tt)
                    qbuf[(size_t)(row + tt) * EP + col] =
                        f2bf(gelu_fast(acc[rf][cf][tt]) * QSCL);
            } else if (sel == 1) {
#pragma unroll
                for (int tt = 0; tt < 4; ++tt)
                    kbuf[(size_t)(row + tt) * KSP + col] = f2bf(gelu_fast(acc[rf][cf][tt]));
            } else {
                const int bb = row >> 11, s = row & 2047;
                ushort4 pk;
                if (col == 200) {
                    pk.x = 0x3F80; pk.y = 0x3F80; pk.z = 0x3F80; pk.w = 0x3F80;
                } else {
                    pk.x = f2bf(gelu_fast(acc[rf][cf][0]));
                    pk.y = f2bf(gelu_fast(acc[rf][cf][1]));
                    pk.z = f2bf(gelu_fast(acc[rf][cf][2]));
                    pk.w = f2bf(gelu_fast(acc[rf][cf][3]));
                }
                *reinterpret_cast<ushort4*>(
                    &vtbuf[((size_t)(bb * EP + col)) * S_ + s]) = pk;
            }
        }
    }
}

// ---------------- Stage 2: flash attention (R22 verbatim) ----------
#define BQ  128
#define BKV 64

#define ASTAGE(KB, VB, KT) do {                                                  \
    const int kv0s = (KT) * BKV;                                                 \
    {   /* K: 32 x 1KB calls, 4 per wave, 2 rows each */                         \
        const int r_in = lane >> 5;                                              \
        const int p = lane & 31;                                                 \
        _Pragma("unroll")                                                        \
        for (int i = 0; i < 4; ++i) {                                            \
            const int j = w * 4 + i;                                             \
            const int row = 2 * j + r_in;                                        \
            gload_lds16(kb_b + (size_t)(kv0s + row) * KSP + ((p ^ ((row << 2) & 31)) * 8),\
                        &KB[j * 512]);                                           \
        }                                                                        \
    }                                                                            \
    {   /* V: 28 x 1KB calls, 8 rows each */                                     \
        const int r_in = lane >> 3;                                              \
        const int p = lane & 7;                                                  \
        _Pragma("unroll")                                                        \
        for (int i = 0; i < 4; ++i) {                                            \
            const int j = i * 8 + w;                                             \
            if (j < 28) {                                                        \
                const int row = 8 * j + r_in;                                    \
                gload_lds16(vt_b + (size_t)row * S_ + kv0s + ((p ^ (row & 7)) * 8),\
                            &VB[j * 512]);                                       \
            }                                                                    \
        }                                                                        \
    }                                                                            \
} while (0)

#define ACOMPUTE(KB, VB) do {                                                    \
    f32x4 sacc[4];                                                               \
    __builtin_amdgcn_s_setprio(1);                                               \
    _Pragma("unroll")                                                            \
    for (int n = 0; n < 4; ++n) {                                                \
        f32x4 a = (f32x4)0.0f;                                                   \
        const int krow = n * 16 + ln15;                                          \
        const unsigned short* kr = &KB[krow * KSP];                              \
        const int rx = (krow << 2) & 31;                                         \
        _Pragma("unroll")                                                        \
        for (int s = 0; s < 7; ++s) {                                            \
            short8 bf = *reinterpret_cast<const short8*>(                        \
                kr + (((s * 4 + g) ^ rx) * 8));                                  \
            a = __builtin_amdgcn_mfma_f32_16x16x32_bf16(qf[s], bf, a, 0, 0, 0);  \
        }                                                                        \
        sacc[n] = a;                                                             \
    }                                                                            \
    __builtin_amdgcn_s_setprio(0);                                               \
    _Pragma("unroll")                                                            \
    for (int n = 0; n < 4; ++n)                                                  \
        _Pragma("unroll")                                                        \
        for (int tt = 0; tt < 4; ++tt)                                           \
            Plds[w][g * 4 + tt][n * 16 + ln15] = f2bf(exp2_fast(sacc[n][tt]));   \
    short8 pf0 = *reinterpret_cast<const short8*>(&Plds[w][ln15][g * 8]);        \
    short8 pf1 = *reinterpret_cast<const short8*>(&Plds[w][ln15][32 + g * 8]);   \
    __builtin_amdgcn_s_setprio(1);                                               \
    _Pragma("unroll")                                                            \
    for (int n = 0; n < 14; ++n) {                                               \
        const int vrow = n * 16 + ln15;                                          \
        const unsigned short* vr = &VB[vrow * 64];                               \
        const int rx = vrow & 7;                                                 \
        short8 b0 = *reinterpret_cast<const short8*>(vr + ((g ^ rx) * 8));       \
        short8 b1 = *reinterpret_cast<const short8*>(vr + (((4 + g) ^ rx) * 8)); \
        o[n] = __builtin_amdgcn_mfma_f32_16x16x32_bf16(pf0, b0, o[n], 0, 0, 0);  \
        o[n] = __builtin_amdgcn_mfma_f32_16x16x32_bf16(pf1, b1, o[n], 0, 0, 0);  \
    }                                                                            \
    __builtin_amdgcn_s_setprio(0);                                               \
} while (0)

__global__ __launch_bounds__(512, 2)
void attn_kernel(const unsigned short* __restrict__ qbuf,
                 const unsigned short* __restrict__ kbuf,
                 const unsigned short* __restrict__ vtbuf,
                 float* __restrict__ out) {
    // XCD-aware role remap: XCD c serves batches {2c, 2c+1} (K/V 1.8MB < 4MB L2)
    const int id = blockIdx.x;            // 0..255
    const int slot = id >> 3;             // 0..31
    const int b = 2 * (id & 7) + (slot >> 4);
    const int q0 = (slot & 15) * BQ;
    const int t = threadIdx.x;
    const int lane = t & 63;
    const int w = t >> 6;                 // 0..7
    const int ln15 = lane & 15;
    const int g = lane >> 4;              // 0..3

    __shared__ __align__(16) unsigned short Ks[2][BKV * KSP];   // 2 x 32KB
    __shared__ __align__(16) unsigned short Vts[2][EP * 64];    // 2 x 28KB
    __shared__ __align__(16) unsigned short Plds[8][16][68];    // 17KB

    // Q fragments: 16 rows per wave (pre-scaled by scale*log2e)
    short8 qf[7];
    {
        const unsigned short* qp =
            qbuf + (size_t)(b * S_ + q0 + w * 16 + ln15) * EP + g * 8;
#pragma unroll
        for (int s = 0; s < 7; ++s)
            qf[s] = *reinterpret_cast<const short8*>(qp + s * 32);
    }

    f32x4 o[14];
#pragma unroll
    for (int i = 0; i < 14; ++i) o[i] = (f32x4)0.0f;

    const unsigned short* kb_b = kbuf + (size_t)b * S_ * KSP;
    const unsigned short* vt_b = vtbuf + (size_t)b * EP * S_;

    ASTAGE(Ks[0], Vts[0], 0);
    __syncthreads();
    for (int kt = 0; kt < S_ / BKV - 1; ++kt) {
        const int cur = kt & 1;
        ASTAGE(Ks[cur ^ 1], Vts[cur ^ 1], kt + 1);
        ACOMPUTE(Ks[cur], Vts[cur]);
        __syncthreads();
    }
    ACOMPUTE(Ks[1], Vts[1]);              // tile 31 (odd -> buffer 1)

    // epilogue: l = o[12] at col 200 (ln15==8); broadcast, normalize, store
    {
        float l[4];
#pragma unroll
        for (int tt = 0; tt < 4; ++tt)
            l[tt] = __shfl(o[12][tt], (lane & 48) + 8, 64);
#pragma unroll
        for (int tt = 0; tt < 4; ++tt) {
            const float inv = 1.0f / l[tt];
            const int row = q0 + w * 16 + g * 4 + tt;
            float* op = out + (size_t)(b * S_ + row) * E_;
#pragma unroll
            for (int n = 0; n < 13; ++n) {
                const int e = n * 16 + ln15;
                if (e < E_) op[e] = o[n][tt] * inv;
            }
        }
    }
}

extern "C" void kernel_launch(void* const* d_in, const int* in_sizes, int n_in,
                              void* d_out, int out_size, void* d_ws, size_t ws_size,
                              hipStream_t stream) {
    const float* x  = (const float*)d_in[0];
    const float* Wq = (const float*)d_in[1];
    const float* Wk = (const float*)d_in[2];
    const float* Wv = (const float*)d_in[3];
    float* out = (float*)d_out;

    unsigned short* wt    = (unsigned short*)d_ws;                 // [3][EP][KP]
    unsigned short* qbuf  = wt + (size_t)3 * EP * KP;              // [M_][EP]
    unsigned short* kbuf  = qbuf + (size_t)M_ * EP;                // [M_][KSP]
    unsigned short* vtbuf = kbuf + (size_t)M_ * KSP;               // [B_][EP][S_]

    prep_w<<<dim3(3 * EP * KP / 256), 256, 0, stream>>>(Wq, Wk, Wv, wt);
    gemm_qkv<<<dim3(256, 3), 256, 0, stream>>>(x, wt, qbuf, kbuf, vtbuf);
    attn_kernel<<<dim3(256), 512, 0, stream>>>(qbuf, kbuf, vtbuf, out);
}